// Round 2
// 664.193 us; speedup vs baseline: 1.0180x; 1.0180x over previous
//
#include <hip/hip_runtime.h>

// GCN layer: out = A_coo @ (X @ W) + b
// N=100000 nodes, E=3200000 edges, D_IN=D_OUT=256.
//
// R5 = R4 with compile fix: __builtin_nontemporal_load requires a native
// vector type, not HIP_vector_type<int,2>. Use i32x2 ext_vector alias.
//
// R4 changes vs R3 (aggregate was 225us @ 49% HBM, VGPR_Count=32 ->
// register-starved gather: only ~4 lines in flight per wave => ~4 TB/s
// Little's-law cap):
//  - aggregate: edge loop unrolled x16 with explicit r[16]/v[16] register
//    batches (forces ~80-96 VGPRs, 5-6 waves/SIMD) for 2-4x the in-flight
//    gathers per wave; eP loads + out stores made nontemporal so the
//    streaming data doesn't evict S rows from L2.
//  - off[] is now N+1 entries (off[N]=E set by add_base) so aggregate
//    doesn't read counts[].
//  - rank_edges / scatter_edges unrolled x8 per thread for more atomics /
//    scattered stores in flight.

typedef __bf16 bf16;
typedef bf16 bf16x4 __attribute__((ext_vector_type(4)));
typedef bf16 bf16x8 __attribute__((ext_vector_type(8)));
typedef float f32x4 __attribute__((ext_vector_type(4)));
typedef int i32x2 __attribute__((ext_vector_type(2)));

#define D_DIM 256

// ---- 1) pack W[256][256] fp32 -> bf16 MFMA B-fragment layout ----
__global__ void pack_w(const float* __restrict__ W, bf16* __restrict__ Wf) {
    int lane = threadIdx.x;           // 64
    int blk  = blockIdx.x;            // 128 = 8 kt * 16 nt
    int kt = blk >> 4, nt = blk & 15;
    int t = lane & 15, q = lane >> 4;
    int krow = kt * 32 + q * 8;
    int col  = nt * 16 + t;
    bf16x8 v;
#pragma unroll
    for (int j = 0; j < 8; ++j)
        v[j] = (bf16)W[(size_t)(krow + j) * D_DIM + col];
    ((bf16x8*)Wf)[(size_t)blk * 64 + lane] = v;
}

// ---- 2) GEMM: support = X @ W (bf16 out). One wave = 16 rows x 256 cols ----
__global__ void gemm_xw(const float* __restrict__ X, const bf16* __restrict__ Wf,
                        bf16* __restrict__ S, int N) {
    int wid  = blockIdx.x * 4 + (threadIdx.x >> 6);
    int base = wid * 16;
    if (base >= N) return;
    int lane = threadIdx.x & 63;
    int t = lane & 15, q = lane >> 4;

    const float* xrow = X + (size_t)(base + t) * D_DIM + q * 8;
    const bf16x8* wf = (const bf16x8*)Wf;

    f32x4 acc[16];
#pragma unroll
    for (int i = 0; i < 16; ++i) acc[i] = (f32x4){0.f, 0.f, 0.f, 0.f};

#pragma unroll
    for (int kt = 0; kt < 8; ++kt) {
        f32x4 x0 = *(const f32x4*)(xrow + kt * 32);
        f32x4 x1 = *(const f32x4*)(xrow + kt * 32 + 4);
        bf16x8 a;
        a[0] = (bf16)x0[0]; a[1] = (bf16)x0[1]; a[2] = (bf16)x0[2]; a[3] = (bf16)x0[3];
        a[4] = (bf16)x1[0]; a[5] = (bf16)x1[1]; a[6] = (bf16)x1[2]; a[7] = (bf16)x1[3];
#pragma unroll
        for (int nt = 0; nt < 16; ++nt) {
            bf16x8 bfr = wf[(size_t)(kt * 16 + nt) * 64 + lane];
            acc[nt] = __builtin_amdgcn_mfma_f32_16x16x32_bf16(a, bfr, acc[nt], 0, 0, 0);
        }
    }

#pragma unroll
    for (int nt = 0; nt < 16; ++nt) {
#pragma unroll
        for (int r = 0; r < 4; ++r) {
            S[(size_t)(base + q * 4 + r) * D_DIM + nt * 16 + t] = (bf16)acc[nt][r];
        }
    }
}

// ---- 3a) histogram + rank: rank[e] = old count of dst. 8 edges/thread ----
__global__ void rank_edges(const int* __restrict__ edst, int* __restrict__ counts,
                           int* __restrict__ erank, int E) {
    int gid  = blockIdx.x * blockDim.x + threadIdx.x;
    int base = gid * 8;
    if (base + 8 <= E) {
        int4 d0 = *(const int4*)(edst + base);
        int4 d1 = *(const int4*)(edst + base + 4);
        int4 r0, r1;
        r0.x = atomicAdd(&counts[d0.x], 1);
        r0.y = atomicAdd(&counts[d0.y], 1);
        r0.z = atomicAdd(&counts[d0.z], 1);
        r0.w = atomicAdd(&counts[d0.w], 1);
        r1.x = atomicAdd(&counts[d1.x], 1);
        r1.y = atomicAdd(&counts[d1.y], 1);
        r1.z = atomicAdd(&counts[d1.z], 1);
        r1.w = atomicAdd(&counts[d1.w], 1);
        *(int4*)(erank + base)     = r0;
        *(int4*)(erank + base + 4) = r1;
    } else {
        for (int e = base; e < E; ++e)
            erank[e] = atomicAdd(&counts[edst[e]], 1);
    }
}

// ---- 3b) per-block exclusive scan (1024 elems/block) ----
__global__ void scan_block(const int* __restrict__ counts, int n,
                           int* __restrict__ local_ex, int* __restrict__ bsums) {
    __shared__ int lds[1024];
    int tid = threadIdx.x;
    int g = blockIdx.x * 1024 + tid;
    int v = (g < n) ? counts[g] : 0;
    lds[tid] = v;
    __syncthreads();
    for (int d = 1; d < 1024; d <<= 1) {
        int add = (tid >= d) ? lds[tid - d] : 0;
        __syncthreads();
        lds[tid] += add;
        __syncthreads();
    }
    if (g < n) local_ex[g] = lds[tid] - v;
    if (tid == 1023) bsums[blockIdx.x] = lds[tid];
}

// ---- 3c) scan of block sums (single block, nb <= 128) ----
__global__ void scan_sums(const int* __restrict__ bsums, int nb, int* __restrict__ bex) {
    __shared__ int lds[128];
    int tid = threadIdx.x;
    int v = (tid < nb) ? bsums[tid] : 0;
    lds[tid] = v;
    __syncthreads();
    for (int d = 1; d < 128; d <<= 1) {
        int add = (tid >= d) ? lds[tid - d] : 0;
        __syncthreads();
        lds[tid] += add;
        __syncthreads();
    }
    if (tid < nb) bex[tid] = lds[tid] - v;
}

// ---- 3d) add block base; also writes sentinel off[n] = E ----
__global__ void add_base(int* __restrict__ off, const int* __restrict__ bex,
                         int n, int E) {
    int g = blockIdx.x * 1024 + threadIdx.x;
    if (g < n) off[g] += bex[blockIdx.x];
    if (g == 0) off[n] = E;
}

// ---- 3e) scatter edges (ATOMIC-FREE): pos = off[dst] + rank. 8/thread ----
__global__ void scatter_edges(const int* __restrict__ esrc, const int* __restrict__ edst,
                              const float* __restrict__ evals, const int* __restrict__ erank,
                              const int* __restrict__ off, i32x2* __restrict__ eP, int E) {
    int gid  = blockIdx.x * blockDim.x + threadIdx.x;
    int base = gid * 8;
    if (base + 8 <= E) {
        int4 s0 = *(const int4*)(esrc + base);
        int4 s1 = *(const int4*)(esrc + base + 4);
        int4 d0 = *(const int4*)(edst + base);
        int4 d1 = *(const int4*)(edst + base + 4);
        int4 r0 = *(const int4*)(erank + base);
        int4 r1 = *(const int4*)(erank + base + 4);
        float4 v0 = *(const float4*)(evals + base);
        float4 v1 = *(const float4*)(evals + base + 4);
        int p0 = off[d0.x] + r0.x;
        int p1 = off[d0.y] + r0.y;
        int p2 = off[d0.z] + r0.z;
        int p3 = off[d0.w] + r0.w;
        int p4 = off[d1.x] + r1.x;
        int p5 = off[d1.y] + r1.y;
        int p6 = off[d1.z] + r1.z;
        int p7 = off[d1.w] + r1.w;
        eP[p0] = (i32x2){s0.x, __float_as_int(v0.x)};
        eP[p1] = (i32x2){s0.y, __float_as_int(v0.y)};
        eP[p2] = (i32x2){s0.z, __float_as_int(v0.z)};
        eP[p3] = (i32x2){s0.w, __float_as_int(v0.w)};
        eP[p4] = (i32x2){s1.x, __float_as_int(v1.x)};
        eP[p5] = (i32x2){s1.y, __float_as_int(v1.y)};
        eP[p6] = (i32x2){s1.z, __float_as_int(v1.z)};
        eP[p7] = (i32x2){s1.w, __float_as_int(v1.w)};
    } else {
        for (int e = base; e < E; ++e) {
            eP[off[edst[e]] + erank[e]] = (i32x2){esrc[e], __float_as_int(evals[e])};
        }
    }
}

// ---- 4) aggregate: one wave per node; lane owns cols [lane*4, lane*4+4) ----
// Edge loop unrolled x16 (explicit register batches -> deep MLP), nontemporal
// eP loads / out stores to preserve L2 for S-row gathers.
__global__ void __launch_bounds__(256) aggregate(
        const bf16* __restrict__ S, const int* __restrict__ off,
        const i32x2* __restrict__ eP, const float* __restrict__ b,
        float* __restrict__ out, int N) {
    int w = blockIdx.x * 4 + (threadIdx.x >> 6);
    if (w >= N) return;
    int lane = threadIdx.x & 63;

    f32x4 acc = ((const f32x4*)b)[lane];

    int e   = off[w];
    int end = off[w + 1];

    // main: 16 edges in flight
    for (; e + 16 <= end; e += 16) {
        i32x2 r[16];
#pragma unroll
        for (int j = 0; j < 16; ++j) r[j] = __builtin_nontemporal_load(&eP[e + j]);
        bf16x4 v[16];
#pragma unroll
        for (int j = 0; j < 16; ++j)
            v[j] = *((const bf16x4*)(S + (size_t)r[j][0] * D_DIM) + lane);
#pragma unroll
        for (int j = 0; j < 16; ++j) {
            float wt = __int_as_float(r[j][1]);
            acc[0] += wt * (float)v[j][0];
            acc[1] += wt * (float)v[j][1];
            acc[2] += wt * (float)v[j][2];
            acc[3] += wt * (float)v[j][3];
        }
    }
    // mid: 4 at a time
    for (; e + 4 <= end; e += 4) {
        i32x2 r[4];
#pragma unroll
        for (int j = 0; j < 4; ++j) r[j] = __builtin_nontemporal_load(&eP[e + j]);
        bf16x4 v[4];
#pragma unroll
        for (int j = 0; j < 4; ++j)
            v[j] = *((const bf16x4*)(S + (size_t)r[j][0] * D_DIM) + lane);
#pragma unroll
        for (int j = 0; j < 4; ++j) {
            float wt = __int_as_float(r[j][1]);
            acc[0] += wt * (float)v[j][0];
            acc[1] += wt * (float)v[j][1];
            acc[2] += wt * (float)v[j][2];
            acc[3] += wt * (float)v[j][3];
        }
    }
    for (; e < end; ++e) {
        i32x2 r = eP[e];
        float wt = __int_as_float(r[1]);
        bf16x4 v = *((const bf16x4*)(S + (size_t)r[0] * D_DIM) + lane);
        acc[0] += wt * (float)v[0];
        acc[1] += wt * (float)v[1];
        acc[2] += wt * (float)v[2];
        acc[3] += wt * (float)v[3];
    }
    __builtin_nontemporal_store(acc, (f32x4*)out + (size_t)w * 64 + lane);
}

extern "C" void kernel_launch(void* const* d_in, const int* in_sizes, int n_in,
                              void* d_out, int out_size, void* d_ws, size_t ws_size,
                              hipStream_t stream) {
    const float* X     = (const float*)d_in[0];
    const int*   esrc  = (const int*)d_in[1];
    const int*   edst  = (const int*)d_in[2];
    const float* evals = (const float*)d_in[3];
    const float* W     = (const float*)d_in[4];
    const float* bias  = (const float*)d_in[5];
    float* out = (float*)d_out;

    const int N = in_sizes[0] / D_DIM;   // 100000
    const int E = in_sizes[1];           // 3200000

    // workspace carve-up (256B aligned)
    auto alignup = [](size_t x) { return (x + 255) & ~(size_t)255; };
    char* ws = (char*)d_ws;
    size_t o = 0;
    bf16* S      = (bf16*)(ws + o); o = alignup(o + (size_t)N * D_DIM * sizeof(bf16));
    int* counts  = (int*)(ws + o);  o = alignup(o + (size_t)N * sizeof(int));
    int* off     = (int*)(ws + o);  o = alignup(o + (size_t)(N + 1) * sizeof(int));
    int* erank   = (int*)(ws + o);  o = alignup(o + (size_t)E * sizeof(int));
    int* bsums   = (int*)(ws + o);  o = alignup(o + 1024 * sizeof(int));
    int* bex     = (int*)(ws + o);  o = alignup(o + 1024 * sizeof(int));
    i32x2* eP    = (i32x2*)(ws + o); o = alignup(o + (size_t)E * sizeof(i32x2));
    bf16* Wf     = (bf16*)(ws + o); o = alignup(o + (size_t)D_DIM * D_DIM * sizeof(bf16));

    const int nb = (N + 1023) / 1024;        // 98 (<=128 required by scan_sums)
    const int nwaves = (N + 15) / 16;        // 6250
    const int nthr8 = (E + 7) / 8;           // threads for 8-edge kernels

    hipMemsetAsync(counts, 0, (size_t)N * sizeof(int), stream);
    pack_w<<<128, 64, 0, stream>>>(W, Wf);
    gemm_xw<<<(nwaves + 3) / 4, 256, 0, stream>>>(X, Wf, S, N);
    rank_edges<<<(nthr8 + 255) / 256, 256, 0, stream>>>(edst, counts, erank, E);
    scan_block<<<nb, 1024, 0, stream>>>(counts, N, off, bsums);
    scan_sums<<<1, 128, 0, stream>>>(bsums, nb, bex);
    add_base<<<nb, 1024, 0, stream>>>(off, bex, N, E);
    scatter_edges<<<(nthr8 + 255) / 256, 256, 0, stream>>>(esrc, edst, evals, erank, off, eP, E);
    aggregate<<<(N + 3) / 4, 256, 0, stream>>>(S, off, eP, bias, out, N);
}